// Round 8
// baseline (206.162 us; speedup 1.0000x reference)
//
#include <hip/hip_runtime.h>

// AdderNet 2D: out[n,f,h,w] = -sum_{c,kh,kw} |W[f,c,kh,kw] - xpad[n,c,h+kh,w+kw]|
// x: (16,64,14,14) fp32, W: (64,64,3,3) fp32, out: (16,64,14,14) fp32
//
// R8 DIAGNOSTIC + lean body. The hot pass repeats REPS=16x inside the
// kernel (acc accumulates all reps, scaled by 1/16 at the end -> not
// elidable, numerically exact to ~1e-3) so the kernel rises above the
// harness's 40us fills and we finally read its VGPR/VALUBusy/Occupancy.
// Body = R7 (lane=f, W in 36 VGPRs, wave-uniform x-row loads, acc[14])
// but with #pragma unroll 1 on the channel loop to cap live ranges
// (~110 VGPR: no spills, no 168-load hoisting).

#define N_ 16
#define C_ 64
#define F_ 64
#define P_ 196
#define REPS 16

__global__ __launch_bounds__(256) void adder2d_kernel(
    const float* __restrict__ x, const float* __restrict__ w,
    float* __restrict__ out)
{
    __shared__ float part[4][64 * 15];   // stride 15 -> conflict-free

    const int tid = threadIdx.x;        // 0..255
    const int row = blockIdx.x;         // 0..13 output row
    const int n   = blockIdx.y;         // 0..15
    const int cs  = blockIdx.z;         // 0..3 channel slice (16 ch)
    const int f   = tid & 63;           // lane = filter
    const int wid = __builtin_amdgcn_readfirstlane(tid >> 6);  // wave 0..3
    const int cbase = cs * 16 + wid * 4;  // this wave's 4 channels

    // W[f][cbase..cbase+3][0..8]: 36 contiguous floats, loaded once
    float Wr[36];
    {
        const float4* wp = (const float4*)(w + f * (C_ * 9) + cbase * 9);
        #pragma unroll
        for (int i = 0; i < 9; ++i) {
            float4 t = wp[i];
            Wr[4 * i + 0] = t.x; Wr[4 * i + 1] = t.y;
            Wr[4 * i + 2] = t.z; Wr[4 * i + 3] = t.w;
        }
    }

    float acc[14];
    #pragma unroll
    for (int p = 0; p < 14; ++p) acc[p] = 0.f;

    #pragma unroll 1
    for (int rep = 0; rep < REPS; ++rep) {
        #pragma unroll 1
        for (int cl = 0; cl < 4; ++cl) {   // keep live state small
            const float* xc = x + (n * C_ + (cbase + cl)) * P_;
            #pragma unroll
            for (int kh = 0; kh < 3; ++kh) {
                const int ir = row + kh - 1;       // input row, -1..14
                float xr[16];
                xr[0] = 0.f; xr[15] = 0.f;
                if (ir >= 0 && ir <= 13) {         // block-uniform branch
                    #pragma unroll
                    for (int j = 0; j < 14; ++j) xr[j + 1] = xc[ir * 14 + j];
                } else {
                    #pragma unroll
                    for (int j = 0; j < 14; ++j) xr[j + 1] = 0.f;
                }
                #pragma unroll
                for (int kw = 0; kw < 3; ++kw) {
                    const float wvv = Wr[cl * 9 + kh * 3 + kw];
                    #pragma unroll
                    for (int p = 0; p < 14; ++p)
                        acc[p] += fabsf(wvv - xr[p + kw]);
                }
            }
        }
    }

    // 4-wave partial reduce in LDS (scale out the reps)
    #pragma unroll
    for (int p = 0; p < 14; ++p)
        part[wid][f * 15 + p] = acc[p] * (1.0f / REPS);
    __syncthreads();

    // 896 outputs this block; atomic add into zeroed d_out
    for (int o = tid; o < 896; o += 256) {
        const int ff = o / 14;
        const int px = o - ff * 14;
        const int a  = ff * 15 + px;
        float s = part[0][a] + part[1][a] + part[2][a] + part[3][a];
        atomicAdd(&out[(n * F_ + ff) * P_ + row * 14 + px], -s);
    }
}

extern "C" void kernel_launch(void* const* d_in, const int* in_sizes, int n_in,
                              void* d_out, int out_size, void* d_ws, size_t ws_size,
                              hipStream_t stream) {
    const float* x = (const float*)d_in[0];
    const float* w = (const float*)d_in[1];
    float* out = (float*)d_out;
    // d_out is re-poisoned 0xAA before every call -> zero it (graph-legal)
    hipMemsetAsync(out, 0, (size_t)out_size * sizeof(float), stream);
    dim3 grid(14, N_, 4);
    adder2d_kernel<<<grid, 256, 0, stream>>>(x, w, out);
}

// Round 9
// 69.277 us; speedup vs baseline: 2.9759x; 2.9759x over previous
//
#include <hip/hip_runtime.h>

// AdderNet 2D: out[n,f,h,w] = -sum_{c,kh,kw} |W[f,c,kh,kw] - xpad[n,c,h+kh,w+kw]|
// x: (16,64,14,14) fp32, W: (64,64,3,3) fp32, out: (16,64,14,14) fp32
//
// R9: lane = f, W in 36 VGPRs (loaded once, constant-indexed, full unroll
// -> no scratch demotion; R8 proved unroll-1 demoted Wr and scalarized x
// loads: VGPR=28, SGPR=112, 40MB scratch FETCH). x rows now come from a
// 3KB LDS tile via wave-uniform ds_read_b128 BROADCASTS (same-address =
// conflict-free, VGPR destinations, immediate offsets) instead of the
// serialized s_load/K$ path that was the 9x wall in R6-R8.
// Grid (14 row, 16 n, 4 cslice) x 256thr; cross-block c-reduce via
// atomicAdd onto memset-zeroed d_out (proven infra from R7).

#define N_ 16
#define C_ 64
#define F_ 64
#define P_ 196

__global__ __launch_bounds__(256, 4) void adder2d_kernel(
    const float* __restrict__ x, const float* __restrict__ w,
    float* __restrict__ out)
{
    // [c(16)][r(3)][col(16, zero-padded)] = 768 floats = 3 KB
    __shared__ __align__(16) float xs[16 * 48];
    __shared__ float part[4][64 * 15];   // stride 15 -> conflict-free

    const int tid = threadIdx.x;        // 0..255
    const int row = blockIdx.x;         // 0..13 output row
    const int n   = blockIdx.y;         // 0..15
    const int cs  = blockIdx.z;         // 0..3 channel slice (16 ch)
    const int f   = tid & 63;           // lane = filter
    const int wid = tid >> 6;           // wave 0..3 -> ch quad
    const int cbase = cs * 16 + wid * 4;

    // ---- stage 16ch x 3 rows x 16 cols (padded) into LDS: 3 stores/thr ----
    #pragma unroll
    for (int i = 0; i < 3; ++i) {
        const int idx = tid + 256 * i;          // 0..767
        const int c   = idx / 48;
        const int rem = idx - c * 48;
        const int r   = rem >> 4;               // 0..2
        const int col = rem & 15;               // 0..15
        const int ir  = row + r - 1;            // input row, -1..14
        float v = 0.f;
        if (col >= 1 && col <= 14 && ir >= 0 && ir <= 13)
            v = x[(n * C_ + cs * 16 + c) * P_ + ir * 14 + (col - 1)];
        xs[idx] = v;
    }

    // ---- W[f][cbase..cbase+3][0..8]: 36 floats, 9 dwordx4, loaded once ----
    float Wr[36];
    {
        const float4* wp = (const float4*)(w + f * (C_ * 9) + cbase * 9);
        #pragma unroll
        for (int i = 0; i < 9; ++i) {
            float4 t = wp[i];
            Wr[4 * i + 0] = t.x; Wr[4 * i + 1] = t.y;
            Wr[4 * i + 2] = t.z; Wr[4 * i + 3] = t.w;
        }
    }

    float acc[14];
    #pragma unroll
    for (int p = 0; p < 14; ++p) acc[p] = 0.f;

    __syncthreads();

    // ---- hot loop: 12 sections of (4 ds_read_b128 broadcast + 84 VALU) ----
    const float* xb = xs + (wid * 4) * 48;   // this wave's ch-quad base
    #pragma unroll
    for (int cl = 0; cl < 4; ++cl) {
        #pragma unroll
        for (int kh = 0; kh < 3; ++kh) {
            const float4* rp = (const float4*)(xb + cl * 48 + kh * 16);
            float4 q0 = rp[0], q1 = rp[1], q2 = rp[2], q3 = rp[3];
            float xr[16] = {q0.x, q0.y, q0.z, q0.w,  q1.x, q1.y, q1.z, q1.w,
                            q2.x, q2.y, q2.z, q2.w,  q3.x, q3.y, q3.z, q3.w};
            #pragma unroll
            for (int kw = 0; kw < 3; ++kw) {
                const float wv = Wr[cl * 9 + kh * 3 + kw];  // const index
                #pragma unroll
                for (int p = 0; p < 14; ++p)
                    acc[p] += fabsf(wv - xr[p + kw]);       // sub + add|.|
            }
        }
    }

    // ---- 4-wave partial reduce in LDS ----
    #pragma unroll
    for (int p = 0; p < 14; ++p) part[wid][f * 15 + p] = acc[p];
    __syncthreads();

    // ---- 896 outputs this block; atomic add into zeroed d_out ----
    for (int o = tid; o < 896; o += 256) {
        const int ff = o / 14;
        const int px = o - ff * 14;
        const int a  = ff * 15 + px;
        float s = part[0][a] + part[1][a] + part[2][a] + part[3][a];
        atomicAdd(&out[(n * F_ + ff) * P_ + row * 14 + px], -s);
    }
}

extern "C" void kernel_launch(void* const* d_in, const int* in_sizes, int n_in,
                              void* d_out, int out_size, void* d_ws, size_t ws_size,
                              hipStream_t stream) {
    const float* x = (const float*)d_in[0];
    const float* w = (const float*)d_in[1];
    float* out = (float*)d_out;
    // d_out is re-poisoned 0xAA before every call -> zero it (graph-legal)
    hipMemsetAsync(out, 0, (size_t)out_size * sizeof(float), stream);
    dim3 grid(14, N_, 4);
    adder2d_kernel<<<grid, 256, 0, stream>>>(x, w, out);
}